// Round 1
// baseline (2213.022 us; speedup 1.0000x reference)
//
#include <hip/hip_runtime.h>

// Correlation layer (FlowNet-style), stride=1, 7x7 window.
// B=8, C=128, H=192, W=448. out[b][k][y][x], k=(dj+3)*7+(di+3),
// out = mean_c first[b,c,y,x]*second[b,c,y+dj,x+di] (zero-padded).

constexpr int Bn = 8, Cn = 128, Hn = 192, Wn = 448;
constexpr int TY  = 16;          // y rows per tile
constexpr int TXQ = 16;          // threads along x
constexpr int TXP = 64;          // x pixels per tile (4 per thread)
constexpr int HR  = TY + 6;      // 22 halo rows staged
constexpr int RW  = TXP + 8;     // 72 floats per staged row (halo 4 each side)
constexpr int NQ  = RW / 4;      // 18 float4 quads per row
constexpr int NTASK = HR * NQ;   // 396 staging quads per channel
constexpr int XT = Wn / TXP;     // 7
constexpr int YT = Hn / TY;      // 12
constexpr int NBLK = XT * YT * Bn; // 672
constexpr int PLANE = Hn * Wn;   // 86016

__global__ __launch_bounds__(256, 2)
void corr_k(const float* __restrict__ first,
            const float* __restrict__ second,
            float* __restrict__ out)
{
    __shared__ __align__(16) float smem[2][HR][RW]; // 12.4 KB double-buffered

    const int tid = threadIdx.x;
    const int tx = tid & (TXQ - 1);
    const int ty = tid >> 4;

    // by slowest: y-adjacent tiles are 56 apart (mult of 8 -> same XCD heuristic)
    const int id = blockIdx.x;
    const int by = id / (XT * Bn);
    const int rr = id - by * (XT * Bn);
    const int bx = rr % XT;
    const int bz = rr / XT;

    const int x0 = bx * TXP;
    const int y0 = by * TY;

    const float* fplane0 = first  + (size_t)bz * Cn * PLANE;
    const float* splane0 = second + (size_t)bz * Cn * PLANE;

    // ---- staging task setup (fixed per thread across all channels) ----
    const int t0 = tid, t1 = tid + 256;
    const bool has1 = (t1 < NTASK);
    const int r0 = t0 / NQ, q0 = t0 - r0 * NQ;
    const int r1 = t1 / NQ, q1 = t1 - r1 * NQ;

    const int gy0 = y0 - 3 + r0, gx0 = x0 - 4 + 4 * q0;
    const int gy1 = y0 - 3 + r1, gx1 = x0 - 4 + 4 * q1;

    bool ok0[4], ok1[4];
    const bool row0ok = (gy0 >= 0) && (gy0 < Hn);
    const bool row1ok = (gy1 >= 0) && (gy1 < Hn);
#pragma unroll
    for (int j = 0; j < 4; ++j) {
        ok0[j] = row0ok && (gx0 + j >= 0) && (gx0 + j < Wn);
        ok1[j] = row1ok && (gx1 + j >= 0) && (gx1 + j < Wn);
    }
    // clamped (always-valid) addresses; OOB elems zeroed via masks
    const int soff0 = min(max(gy0, 0), Hn - 1) * Wn + min(max(gx0, 0), Wn - 4);
    const int soff1 = min(max(gy1, 0), Hn - 1) * Wn + min(max(gx1, 0), Wn - 4);

    const int foff = (y0 + ty) * Wn + x0 + 4 * tx; // this thread's 4 pixels

    auto loadmask = [](const float* p, int off, const bool* ok) {
        float4 v = *reinterpret_cast<const float4*>(p + off);
        v.x = ok[0] ? v.x : 0.0f;
        v.y = ok[1] ? v.y : 0.0f;
        v.z = ok[2] ? v.z : 0.0f;
        v.w = ok[3] ? v.w : 0.0f;
        return v;
    };

    float4 acc[49];
#pragma unroll
    for (int k = 0; k < 49; ++k) acc[k] = make_float4(0.f, 0.f, 0.f, 0.f);

    // ---- prologue: stage channel 0 into buf 0, load first(c=0) ----
    {
        float4 v0 = loadmask(splane0, soff0, ok0);
        *reinterpret_cast<float4*>(&smem[0][r0][4 * q0]) = v0;
        if (has1) {
            float4 v1 = loadmask(splane0, soff1, ok1);
            *reinterpret_cast<float4*>(&smem[0][r1][4 * q1]) = v1;
        }
    }
    float4 fcur = *reinterpret_cast<const float4*>(fplane0 + foff);
    __syncthreads();

    int buf = 0;
    for (int c = 0; c < Cn; ++c) {
        const bool pf = (c + 1 < Cn);
        float4 p0, p1, fnext;
        if (pf) { // issue next channel's loads early (hidden under compute)
            const float* sp = splane0 + (size_t)(c + 1) * PLANE;
            p0 = loadmask(sp, soff0, ok0);
            if (has1) p1 = loadmask(sp, soff1, ok1);
            fnext = *reinterpret_cast<const float4*>(fplane0 + (size_t)(c + 1) * PLANE + foff);
        }

        const float(*sb)[RW] = smem[buf];
#pragma unroll
        for (int dj = 0; dj < 7; ++dj) {
            const float* rp = &sb[ty + dj][4 * tx];
            float4 w0 = *reinterpret_cast<const float4*>(rp);
            float4 w1 = *reinterpret_cast<const float4*>(rp + 4);
            float4 w2 = *reinterpret_cast<const float4*>(rp + 8);
            float w[12] = {w0.x, w0.y, w0.z, w0.w,
                           w1.x, w1.y, w1.z, w1.w,
                           w2.x, w2.y, w2.z, w2.w};
#pragma unroll
            for (int di = 0; di < 7; ++di) {
                float4& a = acc[dj * 7 + di];
                a.x = fmaf(fcur.x, w[1 + di], a.x);
                a.y = fmaf(fcur.y, w[2 + di], a.y);
                a.z = fmaf(fcur.z, w[3 + di], a.z);
                a.w = fmaf(fcur.w, w[4 + di], a.w);
            }
        }

        if (pf) {
            float(*sn)[RW] = smem[buf ^ 1];
            *reinterpret_cast<float4*>(&sn[r0][4 * q0]) = p0;
            if (has1) *reinterpret_cast<float4*>(&sn[r1][4 * q1]) = p1;
            fcur = fnext;
        }
        __syncthreads(); // writes to buf^1 done; reads of buf done
        buf ^= 1;
    }

    // ---- epilogue: mean (/128) and store ----
    const float scale = 1.0f / 128.0f;
    float* op = out + ((size_t)bz * 49) * PLANE + foff;
#pragma unroll
    for (int k = 0; k < 49; ++k) {
        float4 a = acc[k];
        a.x *= scale; a.y *= scale; a.z *= scale; a.w *= scale;
        *reinterpret_cast<float4*>(op + (size_t)k * PLANE) = a;
    }
}

extern "C" void kernel_launch(void* const* d_in, const int* in_sizes, int n_in,
                              void* d_out, int out_size, void* d_ws, size_t ws_size,
                              hipStream_t stream) {
    const float* first  = (const float*)d_in[0];
    const float* second = (const float*)d_in[1];
    // d_in[2] = intStride (always 1 for this problem)
    float* out = (float*)d_out;
    corr_k<<<NBLK, 256, 0, stream>>>(first, second, out);
}